// Round 8
// baseline (621.041 us; speedup 1.0000x reference)
//
#include <hip/hip_runtime.h>

// ---------------- problem constants ----------------
#define N_WORDS 16384
#define MAXL    16
#define VOCABSZ 128
#define EMBD    64
#define HID     256
#define GATES   1024        // 4*HID
#define KTOT    320         // HID + EMBD (x folded into K)
#define AROW    328         // A row stride in shorts (656 B = 640 + 16 pad)
#define M_TILE  64          // words per workgroup
#define NT      256         // word tiles (N_WORDS / M_TILE)

typedef __attribute__((ext_vector_type(8))) short bf16x8;  // 8 bf16 = 4 VGPRs
typedef __attribute__((ext_vector_type(4))) float f32x4;
typedef __attribute__((ext_vector_type(4))) int   i32x4;

// ---------------- workspace layout (bytes) ----------------
// wsw : swizzled weights, A-fragment order: [dir][R 0..63][kk 0..9][lane 0..63][8 bf16]
//       row-tile R covers units 4R..4R+3, rows m = 4*uu + gate_type (unit-major interleave)
#define OFF_WSW   0ul          // 2*64*10*64*16 = 1310720
#define OFF_EMB   1310720ul    // 128*64 bf16 = 16384
#define OFF_BIAS  1327104ul    // 2*1024 f32 = 8192 (interleaved unit-major: [4*unit+type])
#define OFF_SORT  1335296ul    // 16384 ints = 65536
#define OFF_HIST  1400832ul    // 16 ints
#define OFF_BASE  1400896ul    // 16 ints
#define OFF_CNT   1400960ul    // 16 ints
#define OFF_C     1401088ul    // 512 blocks * 4wv * 16rt * 4ct * 64 lanes * 4B = 33554432
                               // fully-coalesced scalar fp32 cell state

__device__ inline short tobf(float f) {           // fp32 -> bf16 RNE
  unsigned u = __float_as_uint(f);
  unsigned r = (u + 0x7fffu + ((u >> 16) & 1u)) >> 16;
  return (short)r;
}
// raw transcendental units via inline asm (assembles per cdna4_isa.md §3; avoids
// precise-div expansion AND builtin-name availability roulette)
__device__ inline float aexp2(float x) { float r; asm("v_exp_f32 %0, %1" : "=v"(r) : "v"(x)); return r; }
__device__ inline float arcp(float x)  { float r; asm("v_rcp_f32 %0, %1" : "=v"(r) : "v"(x)); return r; }
__device__ inline float fsig(float x)   { return arcp(1.0f + aexp2(x * -1.4426950408889634f)); }
__device__ inline float ftanhf(float x) { return 1.0f - 2.0f * arcp(1.0f + aexp2(x * 2.8853900817779268f)); }

// ---------------- prep: weight swizzle into MFMA *A*-fragment layout ----------------
// A[m][k] for 16x16x32: m = lane&15, k = kk*32 + (lane>>4)*8 + j
// row m of row-tile R: unit = 4R + (m>>2), gate type = m&3, gate row g = type*256 + unit
__global__ void prep_w(const float* __restrict__ Wihf, const float* __restrict__ Whhf,
                       const float* __restrict__ Wihb, const float* __restrict__ Whhb,
                       short* __restrict__ wsw) {
  int id = blockIdx.x * 256 + threadIdx.x;       // 2*64*10*64 = 81920
  if (id >= 81920) return;
  int d    = id / 40960;
  int r    = id % 40960;
  int R    = r / 640;
  int r2   = r % 640;
  int kk   = r2 / 64;
  int lane = r2 % 64;
  int m    = lane & 15;
  int unit = R * 4 + (m >> 2);
  int ty   = m & 3;
  int g    = ty * 256 + unit;
  int kb   = kk * 32 + (lane >> 4) * 8;
  const float* Wih = d ? Wihb : Wihf;
  const float* Whh = d ? Whhb : Whhf;
  bf16x8 v;
#pragma unroll
  for (int j = 0; j < 8; ++j) {
    int k = kb + j;
    float f = (k < HID) ? Whh[g * HID + k] : Wih[g * EMBD + (k - HID)];
    v[j] = tobf(f);
  }
  ((bf16x8*)wsw)[id] = v;
}

// emb -> bf16, biases -> interleaved sum ([4*unit+type], matches C-row interleave)
__global__ void prep_misc(const float* __restrict__ emb,
                          const float* __restrict__ bihf, const float* __restrict__ bhhf,
                          const float* __restrict__ bihb, const float* __restrict__ bhhb,
                          short* __restrict__ embw, float* __restrict__ biasg) {
  int id = blockIdx.x * 256 + threadIdx.x;       // 8192 + 2048 = 10240
  if (id < VOCABSZ * EMBD) {
    embw[id] = tobf(emb[id]);
  } else {
    int r = id - VOCABSZ * EMBD;
    if (r < 2048) {
      int d = r >> 10, n = r & 1023;
      int g = (n & 3) * 256 + (n >> 2);
      biasg[r] = d ? (bihb[g] + bhhb[g]) : (bihf[g] + bhhf[g]);
    }
  }
}

// ---------------- length bucketing ----------------
__global__ void k_hist(const int* __restrict__ lengths, int* __restrict__ hist) {
  int id = blockIdx.x * 256 + threadIdx.x;
  if (id < N_WORDS) atomicAdd(&hist[lengths[id] - 1], 1);
}
__global__ void k_scan(const int* __restrict__ hist, int* __restrict__ basep) {
  if (threadIdx.x == 0 && blockIdx.x == 0) {
    int s = 0;
    for (int i = 0; i < 16; ++i) { basep[i] = s; s += hist[i]; }
  }
}
__global__ void k_scat(const int* __restrict__ lengths, const int* __restrict__ basep,
                       int* __restrict__ cnt, int* __restrict__ sorted) {
  int id = blockIdx.x * 256 + threadIdx.x;
  if (id < N_WORDS) {
    int b = lengths[id] - 1;
    int p = basep[b] + atomicAdd(&cnt[b], 1);
    sorted[p] = id;
  }
}

// ---------------- main fused BiLSTM kernel ----------------
// Weights = MFMA A-operand (unit-major gate interleave), [h|x] = B-operand.
// Lane's 4 acc regs = i,f,g,o of ONE (unit,word) -> fully lane-private epilogue.
//   lane owns: unit u = 64*wv + 4*rt + quad, word w = ct*16 + (lane&15)
// R8: __launch_bounds__(256,2) caps unified VGPR+AGPR at 256/wave -> 2 blocks/CU
// co-resident (R7's (256,1) let the allocator exceed 256 -> 1 block/CU, fully
// exposed latency). Weight ping-pong dropped (-40 regs) so 256 fits spill-free;
// the co-resident block hides the per-wtile weight-load latency.
__global__ __launch_bounds__(256, 2) void lstm_main(
    const int* __restrict__ char_ids, const int* __restrict__ lengths,
    const short* __restrict__ wsw, const short* __restrict__ embw,
    const float* __restrict__ biasg, const int* __restrict__ sorted,
    float* __restrict__ cws, float* __restrict__ out) {
  __shared__ __align__(16) short A[M_TILE * AROW];   // [word][ h(256) | x(64) | pad(8) ] bf16
  __shared__ __align__(16) int   charl[M_TILE * 16];
  __shared__ __align__(16) float biasl[GATES];
  __shared__ int lenl[M_TILE];
  __shared__ int swl[M_TILE];

  const int tid  = threadIdx.x;
  const int lane = tid & 63;
  const int wv   = tid >> 6;
  const int quad = lane >> 4;
  const int colc = lane & 15;
  const int pb   = blockIdx.x;
  const int dir  = pb & 1;
  const int qb   = pb >> 1;
  const int tile = (qb & 1) ? (255 - (qb >> 1)) : (qb >> 1);

  // this block's c slice: [wv][rt][ct][lane] scalar fp32 (256 B coalesced per wave access)
  float* cb = cws + (size_t)pb * (4 * 16 * 4 * 64);

  if (tid < M_TILE) {
    int sw = sorted[tile * M_TILE + tid];
    swl[tid]  = sw;
    lenl[tid] = lengths[sw];
  }
  ((f32x4*)biasl)[tid] = ((const f32x4*)(biasg + dir * GATES))[tid];
  for (int i = tid; i < M_TILE * AROW / 2; i += 256) ((int*)A)[i] = 0;     // h=0 init
  for (int i = tid; i < 4 * 16 * 4 * 64 / 4; i += 256)
    ((f32x4*)cb)[i] = (f32x4){0.f, 0.f, 0.f, 0.f};                         // c=0 init
  __syncthreads();

  { // char ids for the tile (via sorted ids)
    int w = tid >> 2, ch = tid & 3;
    ((i32x4*)charl)[tid] = ((const i32x4*)(char_ids + swl[w] * 16))[ch];
  }
  int Lmax = lenl[lane];
  for (int o = 32; o; o >>= 1) { int v = __shfl_xor(Lmax, o, 64); Lmax = Lmax > v ? Lmax : v; }
  __syncthreads();  // charl ready

  // stage x for timestep tt into A cols [256,320): wave w covers words 16w..16w+15, 4 lanes/word
  auto gather_x = [&](int tt) {
    int wl = wv * 16 + (lane >> 2);
    int part = lane & 3;
    int lw = lenl[wl];
    int pos = (dir == 0) ? tt : (lw - 1 - tt);
    pos = pos < 0 ? 0 : (pos > 15 ? 15 : pos);
    int cid = charl[wl * 16 + pos];
    const bf16x8* src = (const bf16x8*)(embw + cid * EMBD + part * 16);
    bf16x8 e0 = src[0], e1 = src[1];
    *(bf16x8*)(A + wl * AROW + HID + part * 16)     = e0;
    *(bf16x8*)(A + wl * AROW + HID + part * 16 + 8) = e1;
  };
  gather_x(0);

  // step-invariant lane constants (word dimension, per col-tile ct)
  int lenw[4], hadrb[4], oadr[4];
#pragma unroll
  for (int ct = 0; ct < 4; ++ct) {
    int wl = ct * 16 + colc;
    lenw[ct]  = lenl[wl];
    hadrb[ct] = wl * AROW + 64 * wv + quad;                  // + 4*rt : bf16 h slot in A
    oadr[ct]  = swl[wl] * 512 + dir * 256 + 64 * wv + quad;  // + 4*rt : fp32 out slot
  }
  const short* wp = wsw + ((size_t)dir * 64 + wv * 16) * 10 * 64 * 8 + lane * 8;
  float* cwl = cb + wv * (16 * 4 * 64) + lane;   // + (rt*4+ct)*64

  __syncthreads();  // x / zeros visible

#pragma unroll 1
  for (int t = 0; t < Lmax; ++t) {
    bf16x8 hx[4][10];  // B fragments: lane = B[k = kk*32 + quad*8 + j][n = ct*16 + colc]
#pragma unroll
    for (int ct = 0; ct < 4; ++ct)
#pragma unroll
      for (int kk = 0; kk < 10; ++kk)
        hx[ct][kk] = *(const bf16x8*)(A + (ct * 16 + colc) * AROW + kk * 32 + quad * 8);

    __syncthreads();  // all waves snapshotted A -> safe to overwrite h/x below

#pragma unroll 1
    for (int rt = 0; rt < 16; ++rt) {
      // issue c + bias loads first so they ride under the weight loads
      float co[4];
#pragma unroll
      for (int ct = 0; ct < 4; ++ct) co[ct] = cwl[(rt * 4 + ct) * 64];  // coalesced
      f32x4 bias4 = *(const f32x4*)(biasl + 256 * wv + 16 * rt + 4 * quad);

      bf16x8 wc[10];  // this row-tile's weight A-fragments (single buffer, no ping-pong)
#pragma unroll
      for (int kk = 0; kk < 10; ++kk) wc[kk] = *(const bf16x8*)(wp + (rt * 10 + kk) * 512);

      f32x4 acc[4];
#pragma unroll
      for (int ct = 0; ct < 4; ++ct) acc[ct] = bias4;
#pragma unroll
      for (int kk = 0; kk < 10; ++kk)
#pragma unroll
        for (int ct = 0; ct < 4; ++ct)  // 4 independent acc chains -> MFMA ILP
          acc[ct] = __builtin_amdgcn_mfma_f32_16x16x32_bf16(wc[kk], hx[ct][kk], acc[ct], 0, 0, 0);

#pragma unroll
      for (int ct = 0; ct < 4; ++ct) {
        // lane-private epilogue: regs = i,f,g,o of (unit 64wv+4rt+quad, word ct*16+colc)
        float ig = fsig(acc[ct][0]);
        float fg = fsig(acc[ct][1]);
        float gg = ftanhf(acc[ct][2]);
        float og = fsig(acc[ct][3]);
        float co_v = co[ct];
        float c2 = fg * co_v + ig * gg;
        float h2 = og * ftanhf(c2);
        bool act = t < lenw[ct];
        cwl[(rt * 4 + ct) * 64] = act ? c2 : co_v;
        if (act) A[hadrb[ct] + 4 * rt] = tobf(h2);              // freeze h when masked
        if (t == lenw[ct] - 1) out[oadr[ct] + 4 * rt] = h2;     // final h in fp32
      }
    }

    gather_x(t + 1);   // x for next step (clamped; dead steps are masked)
    __syncthreads();   // h/x writes visible before next step's reads
  }
}

// ---------------- launch ----------------
extern "C" void kernel_launch(void* const* d_in, const int* in_sizes, int n_in,
                              void* d_out, int out_size, void* d_ws, size_t ws_size,
                              hipStream_t stream) {
  const int*   char_ids = (const int*)d_in[0];
  const int*   lengths  = (const int*)d_in[1];
  const float* emb      = (const float*)d_in[2];
  const float* Wihf     = (const float*)d_in[3];
  const float* Whhf     = (const float*)d_in[4];
  const float* bihf     = (const float*)d_in[5];
  const float* bhhf     = (const float*)d_in[6];
  const float* Wihb     = (const float*)d_in[7];
  const float* Whhb     = (const float*)d_in[8];
  const float* bihb     = (const float*)d_in[9];
  const float* bhhb     = (const float*)d_in[10];

  char* ws = (char*)d_ws;
  short* wsw   = (short*)(ws + OFF_WSW);
  short* embw  = (short*)(ws + OFF_EMB);
  float* biasg = (float*)(ws + OFF_BIAS);
  int*   sortd = (int*)(ws + OFF_SORT);
  int*   hist  = (int*)(ws + OFF_HIST);
  int*   basep = (int*)(ws + OFF_BASE);
  int*   cnt   = (int*)(ws + OFF_CNT);
  float* cws   = (float*)(ws + OFF_C);

  hipMemsetAsync(hist, 0, 192, stream);  // hist + base + cnt
  k_hist<<<64, 256, 0, stream>>>(lengths, hist);
  k_scan<<<1, 64, 0, stream>>>(hist, basep);
  k_scat<<<64, 256, 0, stream>>>(lengths, basep, cnt, sortd);
  prep_w<<<320, 256, 0, stream>>>(Wihf, Whhf, Wihb, Whhb, wsw);
  prep_misc<<<40, 256, 0, stream>>>(emb, bihf, bhhf, bihb, bhhb, embw, biasg);
  lstm_main<<<512, 256, 0, stream>>>(char_ids, lengths, wsw, embw, biasg, sortd,
                                     cws, (float*)d_out);
}

// Round 9
// 581.398 us; speedup vs baseline: 1.0682x; 1.0682x over previous
//
#include <hip/hip_runtime.h>

// ---------------- problem constants ----------------
#define N_WORDS 16384
#define MAXL    16
#define VOCABSZ 128
#define EMBD    64
#define HID     256
#define GATES   1024        // 4*HID
#define KTOT    320         // HID + EMBD (x folded into K)
#define AROW    328         // A row stride in shorts (656 B = 640 + 16 pad)
#define M_TILE  64          // words per workgroup
#define NT      256         // word tiles (N_WORDS / M_TILE)

typedef __attribute__((ext_vector_type(8))) short bf16x8;  // 8 bf16 = 4 VGPRs
typedef __attribute__((ext_vector_type(4))) float f32x4;
typedef __attribute__((ext_vector_type(4))) int   i32x4;

// ---------------- workspace layout (bytes) ----------------
// wsw : swizzled weights, A-fragment order: [dir][R 0..63][kk 0..9][lane 0..63][8 bf16]
//       row-tile R covers units 4R..4R+3, rows m = 4*uu + gate_type (unit-major interleave)
#define OFF_WSW   0ul          // 2*64*10*64*16 = 1310720
#define OFF_EMB   1310720ul    // 128*64 bf16 = 16384
#define OFF_BIAS  1327104ul    // 2*1024 f32 = 8192 (interleaved unit-major: [4*unit+type])
#define OFF_SORT  1335296ul    // 16384 ints = 65536
#define OFF_HIST  1400832ul    // 16 ints
#define OFF_BASE  1400896ul    // 16 ints
#define OFF_CNT   1400960ul    // 16 ints
#define OFF_C     1401088ul    // 512 blocks * 4wv * 16rt * 4ct * 64 lanes * 4B = 33554432
                               // fully-coalesced scalar fp32 cell state

__device__ inline short tobf(float f) {           // fp32 -> bf16 RNE
  unsigned u = __float_as_uint(f);
  unsigned r = (u + 0x7fffu + ((u >> 16) & 1u)) >> 16;
  return (short)r;
}
// raw transcendental units via inline asm (assembles per cdna4_isa.md §3; avoids
// precise-div expansion AND builtin-name availability roulette)
__device__ inline float aexp2(float x) { float r; asm("v_exp_f32 %0, %1" : "=v"(r) : "v"(x)); return r; }
__device__ inline float arcp(float x)  { float r; asm("v_rcp_f32 %0, %1" : "=v"(r) : "v"(x)); return r; }
__device__ inline float fsig(float x)   { return arcp(1.0f + aexp2(x * -1.4426950408889634f)); }
__device__ inline float ftanhf(float x) { return 1.0f - 2.0f * arcp(1.0f + aexp2(x * 2.8853900817779268f)); }

// ---------------- prep: weight swizzle into MFMA *A*-fragment layout ----------------
// A[m][k] for 16x16x32: m = lane&15, k = kk*32 + (lane>>4)*8 + j
// row m of row-tile R: unit = 4R + (m>>2), gate type = m&3, gate row g = type*256 + unit
__global__ void prep_w(const float* __restrict__ Wihf, const float* __restrict__ Whhf,
                       const float* __restrict__ Wihb, const float* __restrict__ Whhb,
                       short* __restrict__ wsw) {
  int id = blockIdx.x * 256 + threadIdx.x;       // 2*64*10*64 = 81920
  if (id >= 81920) return;
  int d    = id / 40960;
  int r    = id % 40960;
  int R    = r / 640;
  int r2   = r % 640;
  int kk   = r2 / 64;
  int lane = r2 % 64;
  int m    = lane & 15;
  int unit = R * 4 + (m >> 2);
  int ty   = m & 3;
  int g    = ty * 256 + unit;
  int kb   = kk * 32 + (lane >> 4) * 8;
  const float* Wih = d ? Wihb : Wihf;
  const float* Whh = d ? Whhb : Whhf;
  bf16x8 v;
#pragma unroll
  for (int j = 0; j < 8; ++j) {
    int k = kb + j;
    float f = (k < HID) ? Whh[g * HID + k] : Wih[g * EMBD + (k - HID)];
    v[j] = tobf(f);
  }
  ((bf16x8*)wsw)[id] = v;
}

// emb -> bf16, biases -> interleaved sum ([4*unit+type], matches C-row interleave)
__global__ void prep_misc(const float* __restrict__ emb,
                          const float* __restrict__ bihf, const float* __restrict__ bhhf,
                          const float* __restrict__ bihb, const float* __restrict__ bhhb,
                          short* __restrict__ embw, float* __restrict__ biasg) {
  int id = blockIdx.x * 256 + threadIdx.x;       // 8192 + 2048 = 10240
  if (id < VOCABSZ * EMBD) {
    embw[id] = tobf(emb[id]);
  } else {
    int r = id - VOCABSZ * EMBD;
    if (r < 2048) {
      int d = r >> 10, n = r & 1023;
      int g = (n & 3) * 256 + (n >> 2);
      biasg[r] = d ? (bihb[g] + bhhb[g]) : (bihf[g] + bhhf[g]);
    }
  }
}

// ---------------- length bucketing ----------------
__global__ void k_hist(const int* __restrict__ lengths, int* __restrict__ hist) {
  int id = blockIdx.x * 256 + threadIdx.x;
  if (id < N_WORDS) atomicAdd(&hist[lengths[id] - 1], 1);
}
__global__ void k_scan(const int* __restrict__ hist, int* __restrict__ basep) {
  if (threadIdx.x == 0 && blockIdx.x == 0) {
    int s = 0;
    for (int i = 0; i < 16; ++i) { basep[i] = s; s += hist[i]; }
  }
}
__global__ void k_scat(const int* __restrict__ lengths, const int* __restrict__ basep,
                       int* __restrict__ cnt, int* __restrict__ sorted) {
  int id = blockIdx.x * 256 + threadIdx.x;
  if (id < N_WORDS) {
    int b = lengths[id] - 1;
    int p = basep[b] + atomicAdd(&cnt[b], 1);
    sorted[p] = id;
  }
}

// ---------------- main fused BiLSTM kernel ----------------
// Weights = MFMA A-operand (unit-major gate interleave), [h|x] = B-operand.
// Lane's 4 acc regs = i,f,g,o of ONE (unit,word) -> lane-private epilogue.
// R9: each t-step runs TWO PASSES over ct-pairs (words 0-31 then 32-63).
// Per pass: snapshot hx for 2 ct (80 regs, not 160) -> full weight ping-pong
// (80 regs) fits under the 2-waves/SIMD unified budget (~200 total) -> R7's
// latency hiding AND R8's 2-blocks/CU occupancy simultaneously.
// Race-safety: pass0 writes h only for words 0-31, pass1 only 32-63; every
// cross-wave write->read pair is separated by >=1 barrier (3 barriers/t).
// Cost: weights stream 2x per t (5.6 GB L2 total) — predicted acceptable.
__global__ __launch_bounds__(256, 2) void lstm_main(
    const int* __restrict__ char_ids, const int* __restrict__ lengths,
    const short* __restrict__ wsw, const short* __restrict__ embw,
    const float* __restrict__ biasg, const int* __restrict__ sorted,
    float* __restrict__ cws, float* __restrict__ out) {
  __shared__ __align__(16) short A[M_TILE * AROW];   // [word][ h(256) | x(64) | pad(8) ] bf16
  __shared__ __align__(16) int   charl[M_TILE * 16];
  __shared__ __align__(16) float biasl[GATES];
  __shared__ int lenl[M_TILE];
  __shared__ int swl[M_TILE];

  const int tid  = threadIdx.x;
  const int lane = tid & 63;
  const int wv   = tid >> 6;
  const int quad = lane >> 4;
  const int colc = lane & 15;
  const int pb   = blockIdx.x;
  const int dir  = pb & 1;
  const int qb   = pb >> 1;
  const int tile = (qb & 1) ? (255 - (qb >> 1)) : (qb >> 1);

  // this block's c slice: [wv][rt][ct][lane] scalar fp32 (256 B coalesced per wave access)
  float* cb = cws + (size_t)pb * (4 * 16 * 4 * 64);

  if (tid < M_TILE) {
    int sw = sorted[tile * M_TILE + tid];
    swl[tid]  = sw;
    lenl[tid] = lengths[sw];
  }
  ((f32x4*)biasl)[tid] = ((const f32x4*)(biasg + dir * GATES))[tid];
  for (int i = tid; i < M_TILE * AROW / 2; i += 256) ((int*)A)[i] = 0;     // h=0 init
  for (int i = tid; i < 4 * 16 * 4 * 64 / 4; i += 256)
    ((f32x4*)cb)[i] = (f32x4){0.f, 0.f, 0.f, 0.f};                         // c=0 init
  __syncthreads();

  { // char ids for the tile (via sorted ids)
    int w = tid >> 2, ch = tid & 3;
    ((i32x4*)charl)[tid] = ((const i32x4*)(char_ids + swl[w] * 16))[ch];
  }
  int Lmax = lenl[lane];
  for (int o = 32; o; o >>= 1) { int v = __shfl_xor(Lmax, o, 64); Lmax = Lmax > v ? Lmax : v; }
  __syncthreads();  // charl ready

  // stage x for timestep tt into A cols [256,320): wave w covers words 16w..16w+15, 4 lanes/word
  auto gather_x = [&](int tt) {
    int wl = wv * 16 + (lane >> 2);
    int part = lane & 3;
    int lw = lenl[wl];
    int pos = (dir == 0) ? tt : (lw - 1 - tt);
    pos = pos < 0 ? 0 : (pos > 15 ? 15 : pos);
    int cid = charl[wl * 16 + pos];
    const bf16x8* src = (const bf16x8*)(embw + cid * EMBD + part * 16);
    bf16x8 e0 = src[0], e1 = src[1];
    *(bf16x8*)(A + wl * AROW + HID + part * 16)     = e0;
    *(bf16x8*)(A + wl * AROW + HID + part * 16 + 8) = e1;
  };
  gather_x(0);

  // step-invariant lane constants (word dimension, per col-tile ct)
  int lenw[4], hadrb[4], oadr[4];
#pragma unroll
  for (int ct = 0; ct < 4; ++ct) {
    int wl = ct * 16 + colc;
    lenw[ct]  = lenl[wl];
    hadrb[ct] = wl * AROW + 64 * wv + quad;                  // + 4*rt : bf16 h slot in A
    oadr[ct]  = swl[wl] * 512 + dir * 256 + 64 * wv + quad;  // + 4*rt : fp32 out slot
  }
  const short* wp = wsw + ((size_t)dir * 64 + wv * 16) * 10 * 64 * 8 + lane * 8;
  float* cwl = cb + wv * (16 * 4 * 64) + lane;   // + (rt*4+ct)*64

  __syncthreads();  // x / zeros visible

#pragma unroll 1
  for (int t = 0; t < Lmax; ++t) {

    // one pass = words [c0*16, c0*16+32): snapshot 2 ct of hx, stream weights w/ ping-pong
    auto pass = [&](const int c0) {
      bf16x8 hx[2][10];  // B frags: lane = B[k = kk*32 + quad*8 + j][n = (c0+ci)*16 + colc]
#pragma unroll
      for (int ci = 0; ci < 2; ++ci)
#pragma unroll
        for (int kk = 0; kk < 10; ++kk)
          hx[ci][kk] = *(const bf16x8*)(A + ((c0 + ci) * 16 + colc) * AROW + kk * 32 + quad * 8);

      __syncthreads();  // all waves snapshotted this pass's words -> safe to write their h

      bf16x8 wA[10], wB[10];
#pragma unroll
      for (int kk = 0; kk < 10; ++kk) wA[kk] = *(const bf16x8*)(wp + kk * 512);

      auto wtile = [&](int rt, bf16x8(&wc)[10], bf16x8(&wn)[10], int pre) {
        float co[2];
#pragma unroll
        for (int ci = 0; ci < 2; ++ci) co[ci] = cwl[(rt * 4 + c0 + ci) * 64];  // coalesced
        f32x4 bias4 = *(const f32x4*)(biasl + 256 * wv + 16 * rt + 4 * quad);
        if (pre >= 0) {  // prefetch next row-tile's weights (vmcnt stays > 0 over MFMAs)
#pragma unroll
          for (int kk = 0; kk < 10; ++kk) wn[kk] = *(const bf16x8*)(wp + (pre * 10 + kk) * 512);
        }
        f32x4 acc[2];
        acc[0] = bias4;
        acc[1] = bias4;
#pragma unroll
        for (int kk = 0; kk < 10; ++kk)
#pragma unroll
          for (int ci = 0; ci < 2; ++ci)  // 2 independent acc chains
            acc[ci] = __builtin_amdgcn_mfma_f32_16x16x32_bf16(wc[kk], hx[ci][kk], acc[ci], 0, 0, 0);

#pragma unroll
        for (int ci = 0; ci < 2; ++ci) {
          const int ct = c0 + ci;
          // lane-private epilogue: regs = i,f,g,o of (unit 64wv+4rt+quad, word ct*16+colc)
          float ig = fsig(acc[ci][0]);
          float fg = fsig(acc[ci][1]);
          float gg = ftanhf(acc[ci][2]);
          float og = fsig(acc[ci][3]);
          float co_v = co[ci];
          float c2 = fg * co_v + ig * gg;
          float h2 = og * ftanhf(c2);
          bool act = t < lenw[ct];
          cwl[(rt * 4 + ct) * 64] = act ? c2 : co_v;
          if (act) A[hadrb[ct] + 4 * rt] = tobf(h2);              // freeze h when masked
          if (t == lenw[ct] - 1) out[oadr[ct] + 4 * rt] = h2;     // final h in fp32
        }
      };

#pragma unroll 1
      for (int rt2 = 0; rt2 < 16; rt2 += 2) {   // ping-pong weight buffers, static indices
        wtile(rt2,     wA, wB, rt2 + 1);
        wtile(rt2 + 1, wB, wA, (rt2 + 2 < 16) ? (rt2 + 2) : -1);
      }
    };

    pass(0);   // words  0..31
    pass(2);   // words 32..63

    gather_x(t + 1);   // x for next step (clamped; dead steps are masked)
    __syncthreads();   // h/x writes visible before next step's snapshots
  }
}

// ---------------- launch ----------------
extern "C" void kernel_launch(void* const* d_in, const int* in_sizes, int n_in,
                              void* d_out, int out_size, void* d_ws, size_t ws_size,
                              hipStream_t stream) {
  const int*   char_ids = (const int*)d_in[0];
  const int*   lengths  = (const int*)d_in[1];
  const float* emb      = (const float*)d_in[2];
  const float* Wihf     = (const float*)d_in[3];
  const float* Whhf     = (const float*)d_in[4];
  const float* bihf     = (const float*)d_in[5];
  const float* bhhf     = (const float*)d_in[6];
  const float* Wihb     = (const float*)d_in[7];
  const float* Whhb     = (const float*)d_in[8];
  const float* bihb     = (const float*)d_in[9];
  const float* bhhb     = (const float*)d_in[10];

  char* ws = (char*)d_ws;
  short* wsw   = (short*)(ws + OFF_WSW);
  short* embw  = (short*)(ws + OFF_EMB);
  float* biasg = (float*)(ws + OFF_BIAS);
  int*   sortd = (int*)(ws + OFF_SORT);
  int*   hist  = (int*)(ws + OFF_HIST);
  int*   basep = (int*)(ws + OFF_BASE);
  int*   cnt   = (int*)(ws + OFF_CNT);
  float* cws   = (float*)(ws + OFF_C);

  hipMemsetAsync(hist, 0, 192, stream);  // hist + base + cnt
  k_hist<<<64, 256, 0, stream>>>(lengths, hist);
  k_scan<<<1, 64, 0, stream>>>(hist, basep);
  k_scat<<<64, 256, 0, stream>>>(lengths, basep, cnt, sortd);
  prep_w<<<320, 256, 0, stream>>>(Wihf, Whhf, Wihb, Whhb, wsw);
  prep_misc<<<40, 256, 0, stream>>>(emb, bihf, bhhf, bihb, bhhb, embw, biasg);
  lstm_main<<<512, 256, 0, stream>>>(char_ids, lengths, wsw, embw, biasg, sortd,
                                     cws, (float*)d_out);
}